// Round 10
// baseline (204.385 us; speedup 1.0000x reference)
//
#include <hip/hip_runtime.h>

typedef _Float16 f16;
typedef _Float16 f16x4 __attribute__((ext_vector_type(4)));
typedef _Float16 f16x8 __attribute__((ext_vector_type(8)));
typedef float f32x4v __attribute__((ext_vector_type(4)));

// ---------------------------------------------------------------------------
// 256x256 tile GEMM, BK=64, 8 waves (2M x 4N), double-buffered LDS (128 KiB),
// FUSED fp32->fp16 staging (no prep kernel):
//   iter t: issue 16 global_load_dwordx4 (fp32, tile t+1)   [early]
//           compute tile t (plain ds_reads + MFMA, compiler-scheduled)
//           cvt fp32->fp16 + 8x ds_write_b128 (XOR-swizzled) [late]
//           __syncthreads()
// Staging assignment: waves 0-3 stage A rows (w&3)*64.., waves 4-7 stage B.
// Thread (srow=lane>>3, scol=lane&7): 8 rows (s*8+srow), cols scol*8..+8.
// Write granule phys = scol ^ srow = logical ^ (row&7)  -> matches read
// swizzle gk = (g ^ (fr&7)) exactly (row&7 == fr&7 on the read side).
// Buffer safety: buf[(t+1)&1] last read in iter t-1, certified by that
// iter's __syncthreads; writes complete before iter t's closing barrier.
// ---------------------------------------------------------------------------
__device__ __forceinline__ void gemm_tile_256(
    const float* __restrict__ A, const float* __restrict__ W,
    const float* __restrict__ bias, f16* __restrict__ C,
    int m0, int n0, int rowShift, int outStride, int rowOff,
    f16* sbuf)
{
  const int t = threadIdx.x;
  const int w = t >> 6, lane = t & 63;
  const int wr = w >> 2, wc = w & 3;        // 2 x 4 wave grid (output)
  const int fr = lane & 15, g = lane >> 4;  // fragment row / k-group
  const int srow = lane >> 3;               // staging row-in-8
  const int scol = lane & 7;                // staging col granule (logical)
  const int gph = scol ^ srow;              // stored (physical) granule

  const bool isB = (w >= 4);
  const int rb = (w & 3) * 64;              // 64 rows per wave
  const float* src = isB
      ? (W + (long long)(n0 + rb + srow) * 1024 + scol * 8)
      : (A + (long long)(m0 + rb + srow) * 1024 + scol * 8);
  f16* dstBase = sbuf + (isB ? 16384 : 0) + (rb + srow) * 64 + gph * 8;

  float4 v0[8], v1[8];   // staged fp32 (64 VGPRs, live within one iter)

#define SLOAD(k0_)                                                           \
  {                                                                          \
    _Pragma("unroll") for (int s = 0; s < 8; ++s) {                          \
      const float* p_ = src + (long long)s * 8192 + (k0_);                   \
      v0[s] = *(const float4*)p_;                                            \
      v1[s] = *(const float4*)(p_ + 4);                                      \
    }                                                                        \
  }
#define SWRITE(bufsel)                                                       \
  {                                                                          \
    f16* db_ = dstBase + ((bufsel) << 15);                                   \
    _Pragma("unroll") for (int s = 0; s < 8; ++s) {                          \
      f16x8 hv_;                                                             \
      hv_[0] = (f16)v0[s].x; hv_[1] = (f16)v0[s].y;                          \
      hv_[2] = (f16)v0[s].z; hv_[3] = (f16)v0[s].w;                          \
      hv_[4] = (f16)v1[s].x; hv_[5] = (f16)v1[s].y;                          \
      hv_[6] = (f16)v1[s].z; hv_[7] = (f16)v1[s].w;                          \
      *(f16x8*)(db_ + s * 512) = hv_;                                        \
    }                                                                        \
  }

  // fragment read offsets (f16 units), granule XOR-swizzled
  const int gk0 = ((0 + g) ^ (fr & 7)) * 8;   // k-half 0
  const int gk1 = ((4 + g) ^ (fr & 7)) * 8;   // k-half 1
  const int aoff = (wr * 128 + fr) * 64;
  const int boff = (wc * 64 + fr) * 64;

  f32x4v acc[8][4];
#pragma unroll
  for (int i = 0; i < 8; ++i)
#pragma unroll
    for (int j = 0; j < 4; ++j) acc[i][j] = (f32x4v){0.f, 0.f, 0.f, 0.f};

  // prologue: tile 0 staged synchronously
  SLOAD(0);
  SWRITE(0);
  __syncthreads();

  for (int tt = 0; tt < 16; ++tt) {
    const f16* ab = sbuf + ((tt & 1) << 15);
    const f16* bb = ab + 16384;

    if (tt < 15) SLOAD((tt + 1) * 64);    // issue early: lands under compute
    __builtin_amdgcn_sched_barrier(0);    // pin load issue before compute

    // plain reads + MFMAs: compiler emits fine-grained counted lgkmcnt
    f16x8 a0[8], b0[4], a1[8], b1[4];
#pragma unroll
    for (int i = 0; i < 8; ++i)
      a0[i] = *(const f16x8*)(ab + aoff + i * 1024 + gk0);
#pragma unroll
    for (int j = 0; j < 4; ++j)
      b0[j] = *(const f16x8*)(bb + boff + j * 1024 + gk0);
#pragma unroll
    for (int i = 0; i < 8; ++i)
#pragma unroll
      for (int j = 0; j < 4; ++j)
        acc[i][j] = __builtin_amdgcn_mfma_f32_16x16x32_f16(a0[i], b0[j],
                                                           acc[i][j], 0, 0, 0);
#pragma unroll
    for (int i = 0; i < 8; ++i)
      a1[i] = *(const f16x8*)(ab + aoff + i * 1024 + gk1);
#pragma unroll
    for (int j = 0; j < 4; ++j)
      b1[j] = *(const f16x8*)(bb + boff + j * 1024 + gk1);
#pragma unroll
    for (int i = 0; i < 8; ++i)
#pragma unroll
      for (int j = 0; j < 4; ++j)
        acc[i][j] = __builtin_amdgcn_mfma_f32_16x16x32_f16(a1[i], b1[j],
                                                           acc[i][j], 0, 0, 0);

    if (tt < 15) SWRITE((tt + 1) & 1);    // cvt + swizzled ds_write (late)

    __syncthreads();   // tile t+1 resident; all reads of tile tt complete
  }
#undef SLOAD
#undef SWRITE

  // ---- epilogue: acc -> Cs[256][256] (XOR-swizzled) -> coalesced stores ----
  f16* Cs = sbuf;
  float bn[4];
#pragma unroll
  for (int j = 0; j < 4; ++j) bn[j] = bias[n0 + wc * 64 + j * 16 + fr];
#pragma unroll
  for (int i = 0; i < 8; ++i) {
#pragma unroll
    for (int j = 0; j < 4; ++j) {
#pragma unroll
      for (int v = 0; v < 4; ++v) {
        // C/D layout: col = lane&15, row = (lane>>4)*4 + v
        int row = wr * 128 + i * 16 + g * 4 + v;
        int col = wc * 64 + j * 16 + fr;
        Cs[row * 256 + (col ^ (((row >> 2) & 7) << 3))] =
            (f16)(acc[i][j][v] + bn[j]);
      }
    }
  }
  __syncthreads();

  const int rowMask = (1 << rowShift) - 1;
  const int row = t >> 1, half = t & 1;
  const int csw = ((row >> 2) & 7) << 3;
  const int arow = m0 + row;
  const int orow = (arow >> rowShift) * outStride + (arow & rowMask) + rowOff;
  f16* dst = C + (long long)orow * 1024 + n0 + half * 128;
  const f16* srcr = Cs + row * 256;
#pragma unroll
  for (int c = 0; c < 16; ++c)
    *(f16x8*)(dst + c * 8) = *(const f16x8*)(srcr + ((half * 128 + c * 8) ^ csw));
}

// ---------------------------------------------------------------------------
// All five projection GEMMs in ONE launch, reading fp32 inputs directly.
// 704 blocks = 8 * 88 (bijective XCD swizzle). v<512: K/V body (M=16384);
// v>=512: Q-side (M=4096): z=0 -> Qh, z=1 -> Kh title, z=2 -> Vh title.
// ---------------------------------------------------------------------------
__global__ __launch_bounds__(512, 1) void gemm_all(
    const float* __restrict__ Q_seq, const float* __restrict__ K_seq,
    const float* __restrict__ V_seq,
    const float* __restrict__ Wq, const float* __restrict__ Wk,
    const float* __restrict__ Wv,
    const float* __restrict__ bq, const float* __restrict__ bk,
    const float* __restrict__ bv,
    f16* __restrict__ Qh, f16* __restrict__ Kh, f16* __restrict__ Vh)
{
  __shared__ __align__(16) f16 sbuf[65536];   // 128 KiB
  const int bid = blockIdx.x;
  const int v = (bid & 7) * 88 + (bid >> 3);

  const float* A;
  const float* W;
  const float* bias;
  f16* C;
  int m0, n0, rowShift, outStride, rowOff;

  if (v < 512) {
    const int z = v >> 8, rem = v & 255;
    A = z ? V_seq : K_seq;
    W = z ? Wv : Wk;
    bias = z ? bv : bk;
    C = z ? Vh : Kh;
    m0 = (rem >> 2) * 256; n0 = (rem & 3) * 256;
    rowShift = 7; outStride = 160; rowOff = 0;
  } else {
    const int u = v - 512;
    const int z = u >> 6, rem = u & 63;
    A = Q_seq;
    W = (z == 0) ? Wq : (z == 1) ? Wk : Wv;
    bias = (z == 0) ? bq : (z == 1) ? bk : bv;
    C = (z == 0) ? Qh : (z == 1) ? Kh : Vh;
    m0 = (rem >> 2) * 256; n0 = (rem & 3) * 256;
    rowShift = 5;
    outStride = (z == 0) ? 32 : 160;
    rowOff = (z == 0) ? 0 : 128;
  }
  gemm_tile_256(A, W, bias, C, m0, n0, rowShift, outStride, rowOff, sbuf);
}

// ---------------------------------------------------------------------------
// MFMA attention: one block per (b,h), 4 waves. (unchanged)
// ---------------------------------------------------------------------------
__global__ __launch_bounds__(256) void attn_kernel(
    const f16* __restrict__ Qh, const f16* __restrict__ Kh,
    const f16* __restrict__ Vh,
    const float* __restrict__ title, const float* __restrict__ body,
    float* __restrict__ out)
{
  __shared__ __align__(16) f16 Qs[32 * 72];    // stride 144B (b128-friendly)
  __shared__ __align__(16) f16 Ks[160 * 72];   // reused as Ps[32][168] (336B)
  __shared__ __align__(16) f16 Vs[160 * 68];   // stride 136B (2-way max on u16)
  __shared__ float rs[4][32];
  __shared__ float invs[32];

  const int bh = blockIdx.x, b = bh >> 4, h = bh & 15;
  const int t = threadIdx.x, w = t >> 6, lane = t & 63;
  const int c = lane & 15, g = lane >> 4;

  const long long qbase = ((long long)(b * 32) << 10) + h * 64;
  const long long kbase = ((long long)(b * 160) << 10) + h * 64;

  {
    int row = t >> 3, ch = t & 7;
    *(f16x8*)(Qs + row * 72 + ch * 8) =
        *(const f16x8*)(Qh + qbase + (long long)row * 1024 + ch * 8);
  }
#pragma unroll
  for (int r = 0; r < 5; ++r) {
    int i = t + r * 256;
    int row = i >> 3, ch = i & 7;
    *(f16x8*)(Ks + row * 72 + ch * 8) =
        *(const f16x8*)(Kh + kbase + (long long)row * 1024 + ch * 8);
    f16x8 vv = *(const f16x8*)(Vh + kbase + (long long)row * 1024 + ch * 8);
    f16x4 vlo = __builtin_shufflevector(vv, vv, 0, 1, 2, 3);
    f16x4 vhi = __builtin_shufflevector(vv, vv, 4, 5, 6, 7);
    *(f16x4*)(Vs + row * 68 + ch * 8) = vlo;
    *(f16x4*)(Vs + row * 68 + ch * 8 + 4) = vhi;
  }
  __syncthreads();

  f16x8 qf[2][2];
#pragma unroll
  for (int qt = 0; qt < 2; ++qt)
#pragma unroll
    for (int s = 0; s < 2; ++s)
      qf[qt][s] = *(const f16x8*)(Qs + (qt * 16 + c) * 72 + s * 32 + g * 8);

  const int cnt = (w < 2) ? 3 : 2;
  const int tile0 = (w < 2) ? w * 3 : 6 + (w - 2) * 2;

  f16x4 pp[3][2];
  float rsum[2] = {0.f, 0.f};

#pragma unroll
  for (int i = 0; i < 3; ++i) {
    if (i < cnt) {
      const int kt = tile0 + i;
      f16x8 kf0 = *(const f16x8*)(Ks + (kt * 16 + c) * 72 + 0 + g * 8);
      f16x8 kf1 = *(const f16x8*)(Ks + (kt * 16 + c) * 72 + 32 + g * 8);
#pragma unroll
      for (int qt = 0; qt < 2; ++qt) {
        f32x4v s4 = (f32x4v){0.f, 0.f, 0.f, 0.f};
        s4 = __builtin_amdgcn_mfma_f32_16x16x32_f16(kf0, qf[qt][0], s4, 0, 0, 0);
        s4 = __builtin_amdgcn_mfma_f32_16x16x32_f16(kf1, qf[qt][1], s4, 0, 0, 0);
        float4 m4;
        if (kt < 8) {
          m4 = *(const float4*)(body +
                ((long long)(b * 32 + qt * 16 + c)) * 128 + kt * 16 + 4 * g);
        } else {
          m4 = *(const float4*)(title + b * 32 + (kt - 8) * 16 + 4 * g);
        }
        float e0 = __expf(s4[0] * 0.125f) * m4.x;
        float e1 = __expf(s4[1] * 0.125f) * m4.y;
        float e2 = __expf(s4[2] * 0.125f) * m4.z;
        float e3 = __expf(s4[3] * 0.125f) * m4.w;
        rsum[qt] += (e0 + e1) + (e2 + e3);
        f16x4 p4;
        p4.x = (f16)e0; p4.y = (f16)e1; p4.z = (f16)e2; p4.w = (f16)e3;
        pp[i][qt] = p4;
      }
    }
  }

#pragma unroll
  for (int qt = 0; qt < 2; ++qt) {
    rsum[qt] += __shfl_xor(rsum[qt], 16);
    rsum[qt] += __shfl_xor(rsum[qt], 32);
  }
  if (lane < 16) {
    rs[w][c] = rsum[0];
    rs[w][16 + c] = rsum[1];
  }
  __syncthreads();

  f16* Ps = Ks;
#pragma unroll
  for (int i = 0; i < 3; ++i) {
    if (i < cnt) {
      const int kt = tile0 + i;
#pragma unroll
      for (int qt = 0; qt < 2; ++qt)
        *(f16x4*)(Ps + (qt * 16 + c) * 168 + kt * 16 + 4 * g) = pp[i][qt];
    }
  }
  if (t < 32) {
    float ssum = rs[0][t] + rs[1][t] + rs[2][t] + rs[3][t];
    invs[t] = title[b * 32 + t] / (ssum + 1e-8f);
  }
  __syncthreads();

  f32x4v o[2] = {(f32x4v){0.f, 0.f, 0.f, 0.f}, (f32x4v){0.f, 0.f, 0.f, 0.f}};
#pragma unroll
  for (int s = 0; s < 5; ++s) {
    f16x8 vf;
#pragma unroll
    for (int j = 0; j < 8; ++j)
      vf[j] = Vs[(32 * s + 8 * g + j) * 68 + 16 * w + c];
#pragma unroll
    for (int qt = 0; qt < 2; ++qt) {
      f16x8 pf = *(const f16x8*)(Ps + (qt * 16 + c) * 168 + s * 32 + g * 8);
      o[qt] = __builtin_amdgcn_mfma_f32_16x16x32_f16(pf, vf, o[qt], 0, 0, 0);
    }
  }

#pragma unroll
  for (int qt = 0; qt < 2; ++qt) {
#pragma unroll
    for (int v = 0; v < 4; ++v) {
      int q = qt * 16 + 4 * g + v;
      out[((long long)(b * 32 + q) << 10) + h * 64 + 16 * w + c] =
          o[qt][v] * invs[q];
    }
  }
}

// ---------------------------------------------------------------------------
extern "C" void kernel_launch(void* const* d_in, const int* in_sizes, int n_in,
                              void* d_out, int out_size, void* d_ws, size_t ws_size,
                              hipStream_t stream) {
  const float* Q_seq = (const float*)d_in[0];
  const float* K_seq = (const float*)d_in[1];
  const float* V_seq = (const float*)d_in[2];
  const float* title = (const float*)d_in[3];
  const float* body  = (const float*)d_in[4];
  const float* Wq = (const float*)d_in[5];
  const float* bq = (const float*)d_in[6];
  const float* Wk = (const float*)d_in[7];
  const float* bk = (const float*)d_in[8];
  const float* Wv = (const float*)d_in[9];
  const float* bv = (const float*)d_in[10];
  float* out = (float*)d_out;

  f16* ws = (f16*)d_ws;
  f16* Qh = ws;                   // [B*32][1024]
  f16* Kh = Qh + 4194304;         // [B*160][1024]
  f16* Vh = Kh + 20971520;        // [B*160][1024]

  gemm_all<<<704, 512, 0, stream>>>(Q_seq, K_seq, V_seq, Wq, Wk, Wv,
                                    bq, bk, bv, Qh, Kh, Vh);
  attn_kernel<<<2048, 256, 0, stream>>>(Qh, Kh, Vh, title, body, out);
}

// Round 11
// 185.237 us; speedup vs baseline: 1.1034x; 1.1034x over previous
//
#include <hip/hip_runtime.h>

typedef _Float16 f16;
typedef _Float16 f16x4 __attribute__((ext_vector_type(4)));
typedef _Float16 f16x8 __attribute__((ext_vector_type(8)));
typedef float f32x4v __attribute__((ext_vector_type(4)));

#define AS1 __attribute__((address_space(1)))
#define AS3 __attribute__((address_space(3)))

// async global->LDS, 16B per lane; LDS dest = wave-uniform base + lane*16
__device__ __forceinline__ void gload_lds16(const f16* g, f16* l) {
  __builtin_amdgcn_global_load_lds((const AS1 unsigned int*)g,
                                   (AS3 unsigned int*)l, 16, 0, 0);
}

// ---------------------------------------------------------------------------
// prep: fp32 -> fp16 conversions, 8 elems/thread (2x float4 -> 1x f16x8).
// ---------------------------------------------------------------------------
__global__ __launch_bounds__(256) void prep_kernel(
    const float* __restrict__ Q_seq, const float* __restrict__ K_seq,
    const float* __restrict__ V_seq,
    const float* __restrict__ Wq, const float* __restrict__ Wk,
    const float* __restrict__ Wv,
    f16* __restrict__ Qb, f16* __restrict__ Kb, f16* __restrict__ Vb,
    f16* __restrict__ Wqb, f16* __restrict__ Wkb, f16* __restrict__ Wvb)
{
  const long long g = (long long)blockIdx.x * 256 + threadIdx.x;
  const float* s;
  f16* d;
  if (g < 524288) {
    s = Q_seq + g * 8; d = Qb + g * 8;
  } else if (g < 2621440) {
    long long e = (g - 524288) * 8; s = K_seq + e; d = Kb + e;
  } else if (g < 4718592) {
    long long e = (g - 2621440) * 8; s = V_seq + e; d = Vb + e;
  } else if (g < 4849664) {
    long long e = (g - 4718592) * 8; s = Wq + e; d = Wqb + e;
  } else if (g < 4980736) {
    long long e = (g - 4849664) * 8; s = Wk + e; d = Wkb + e;
  } else {
    long long e = (g - 4980736) * 8; s = Wv + e; d = Wvb + e;
  }
  float4 v0 = *(const float4*)s;
  float4 v1 = *(const float4*)(s + 4);
  f16x8 o;
  o[0] = (f16)v0.x; o[1] = (f16)v0.y; o[2] = (f16)v0.z; o[3] = (f16)v0.w;
  o[4] = (f16)v1.x; o[5] = (f16)v1.y; o[6] = (f16)v1.z; o[7] = (f16)v1.w;
  *(f16x8*)d = o;
}

// ---------------------------------------------------------------------------
// 256x256 tile GEMM, BK=64, 8 waves (2M x 4N), double-buffered LDS (128 KiB).
// Phase-interleaved schedule (m201-style, 4 phases per K-tile):
//   phase 0: stage 3 units -> vmcnt(3) -> barrier -> B(8)+A_q0(4) reads +
//            16 MFMA (compiler-scheduled counted lgkmcnt) -> barrier
//   phase q=1..3: A_q reads (4) + stage [3,2,0] units -> barrier ->
//            16 MFMA -> barrier
// NO asm lgkmcnt, NO sched_barrier walls (m141 lesson). setprio around MFMA.
// Stage unit = 1 gload_lds/thread (8KB); K-tile = 8 units into the opposite
// buffer (free since prior iteration's final barrier). vmcnt(3) at phase 0
// certifies the current tile while 3 newest units stay in flight.
// T2: XOR granule swizzle (phys = log ^ (row&7)), staged via pre-swizzled
// global source (LDS dest linear), read with matching XOR.
// ---------------------------------------------------------------------------
__device__ __forceinline__ void gemm_tile_256(
    const f16* __restrict__ A, const f16* __restrict__ W,
    const float* __restrict__ bias, f16* __restrict__ C,
    int m0, int n0, int rowShift, int outStride, int rowOff,
    f16* sbuf)
{
  const int t = threadIdx.x;
  const int w = t >> 6, lane = t & 63;
  const int wr = w >> 2, wc = w & 3;        // 2 x 4 wave grid
  const int fr = lane & 15, g = lane >> 4;  // fragment row / k-group
  const int trow = t >> 3;                  // staging: row-in-64 unit
  const int kgr = (t & 7) ^ (trow & 7);     // staging: pre-swizzled k-granule

  const f16* aS = A + (long long)(m0 + trow) * 1024 + kgr * 8;
  const f16* bS = W + (long long)(n0 + trow) * 1024 + kgr * 8;
  // unit u: u<4 -> A rows u*64.., u>=4 -> B rows (u-4)*64..
  // LDS dest (f16): bufbase + u*4096 + w*512 (+ lane*16B by HW)

#define STAGE_UNIT(u, tile)                                                  \
  gload_lds16(((u) < 4 ? aS + ((u) * 64) * 1024 : bS + (((u) - 4) * 64) * 1024) \
                  + (tile) * 64,                                             \
              sbuf + (((tile) & 1) << 15) + (u) * 4096 + w * 512)

  // fragment read offsets (f16 units), granule XOR-swizzled
  const int gk0 = ((0 + g) ^ (fr & 7)) * 8;   // k-half 0
  const int gk1 = ((4 + g) ^ (fr & 7)) * 8;   // k-half 1
  const int boff = (wc * 64 + fr) * 64;

  f32x4v acc[8][4];
#pragma unroll
  for (int i = 0; i < 8; ++i)
#pragma unroll
    for (int j = 0; j < 4; ++j) acc[i][j] = (f32x4v){0.f, 0.f, 0.f, 0.f};

  // prologue: tile 0 fully staged
#pragma unroll
  for (int u = 0; u < 8; ++u) STAGE_UNIT(u, 0);
  __syncthreads();

  for (int tt = 0; tt < 16; ++tt) {
    const f16* ab = sbuf + ((tt & 1) << 15);
    const f16* bb = ab + 16384;

    f16x8 bv0[4], bv1[4];

    // ---------- phase 0: certify tile tt, B + A-quadrant 0 ----------
    if (tt < 15) {
      STAGE_UNIT(0, tt + 1); STAGE_UNIT(1, tt + 1); STAGE_UNIT(2, tt + 1);
      asm volatile("s_waitcnt vmcnt(3)" ::: "memory");
    } else {
      asm volatile("s_waitcnt vmcnt(0)" ::: "memory");
    }
    __builtin_amdgcn_s_barrier();   // tile tt visible to all waves

    {
      const int aoff = (wr * 128 + 0 * 32 + fr) * 64;
#pragma unroll
      for (int j = 0; j < 4; ++j) {
        bv0[j] = *(const f16x8*)(bb + boff + j * 1024 + gk0);
        bv1[j] = *(const f16x8*)(bb + boff + j * 1024 + gk1);
      }
      f16x8 a00 = *(const f16x8*)(ab + aoff + gk0);
      f16x8 a10 = *(const f16x8*)(ab + aoff + 1024 + gk0);
      f16x8 a01 = *(const f16x8*)(ab + aoff + gk1);
      f16x8 a11 = *(const f16x8*)(ab + aoff + 1024 + gk1);
      __builtin_amdgcn_s_setprio(1);
#pragma unroll
      for (int j = 0; j < 4; ++j) {
        acc[0][j] = __builtin_amdgcn_mfma_f32_16x16x32_f16(a00, bv0[j], acc[0][j], 0, 0, 0);
        acc[1][j] = __builtin_amdgcn_mfma_f32_16x16x32_f16(a10, bv0[j], acc[1][j], 0, 0, 0);
      }
#pragma unroll
      for (int j = 0; j < 4; ++j) {
        acc[0][j] = __builtin_amdgcn_mfma_f32_16x16x32_f16(a01, bv1[j], acc[0][j], 0, 0, 0);
        acc[1][j] = __builtin_amdgcn_mfma_f32_16x16x32_f16(a11, bv1[j], acc[1][j], 0, 0, 0);
      }
      __builtin_amdgcn_s_setprio(0);
    }
    __builtin_amdgcn_s_barrier();

    // ---------- phases 1..3: A-quadrant q, stage spread [3,2,0] ----------
#pragma unroll
    for (int q = 1; q < 4; ++q) {
      const int aoff = (wr * 128 + q * 32 + fr) * 64;
      f16x8 a00 = *(const f16x8*)(ab + aoff + gk0);
      f16x8 a10 = *(const f16x8*)(ab + aoff + 1024 + gk0);
      f16x8 a01 = *(const f16x8*)(ab + aoff + gk1);
      f16x8 a11 = *(const f16x8*)(ab + aoff + 1024 + gk1);
      if (tt < 15) {
        if (q == 1) { STAGE_UNIT(3, tt + 1); STAGE_UNIT(4, tt + 1); STAGE_UNIT(5, tt + 1); }
        if (q == 2) { STAGE_UNIT(6, tt + 1); STAGE_UNIT(7, tt + 1); }
      }
      __builtin_amdgcn_s_barrier();   // waves aligned: reads in flight
      __builtin_amdgcn_s_setprio(1);
#pragma unroll
      for (int j = 0; j < 4; ++j) {
        acc[q * 2 + 0][j] = __builtin_amdgcn_mfma_f32_16x16x32_f16(a00, bv0[j], acc[q * 2 + 0][j], 0, 0, 0);
        acc[q * 2 + 1][j] = __builtin_amdgcn_mfma_f32_16x16x32_f16(a10, bv0[j], acc[q * 2 + 1][j], 0, 0, 0);
      }
#pragma unroll
      for (int j = 0; j < 4; ++j) {
        acc[q * 2 + 0][j] = __builtin_amdgcn_mfma_f32_16x16x32_f16(a01, bv1[j], acc[q * 2 + 0][j], 0, 0, 0);
        acc[q * 2 + 1][j] = __builtin_amdgcn_mfma_f32_16x16x32_f16(a11, bv1[j], acc[q * 2 + 1][j], 0, 0, 0);
      }
      __builtin_amdgcn_s_setprio(0);
      __builtin_amdgcn_s_barrier();
    }
  }
#undef STAGE_UNIT
  __syncthreads();   // drain everything before LDS reuse

  // ---- epilogue: acc -> Cs[256][256] (XOR-swizzled) -> coalesced stores ----
  f16* Cs = sbuf;
  float bn[4];
#pragma unroll
  for (int j = 0; j < 4; ++j) bn[j] = bias[n0 + wc * 64 + j * 16 + fr];
#pragma unroll
  for (int i = 0; i < 8; ++i) {
#pragma unroll
    for (int j = 0; j < 4; ++j) {
#pragma unroll
      for (int v = 0; v < 4; ++v) {
        // C/D layout: col = lane&15, row = (lane>>4)*4 + v
        int row = wr * 128 + i * 16 + g * 4 + v;
        int col = wc * 64 + j * 16 + fr;
        Cs[row * 256 + (col ^ (((row >> 2) & 7) << 3))] =
            (f16)(acc[i][j][v] + bn[j]);
      }
    }
  }
  __syncthreads();

  const int rowMask = (1 << rowShift) - 1;
  const int row = t >> 1, half = t & 1;
  const int csw = ((row >> 2) & 7) << 3;
  const int arow = m0 + row;
  const int orow = (arow >> rowShift) * outStride + (arow & rowMask) + rowOff;
  f16* dst = C + (long long)orow * 1024 + n0 + half * 128;
  const f16* srcr = Cs + row * 256;
#pragma unroll
  for (int c = 0; c < 16; ++c)
    *(f16x8*)(dst + c * 8) = *(const f16x8*)(srcr + ((half * 128 + c * 8) ^ csw));
}

// ---------------------------------------------------------------------------
// All five projection GEMMs in ONE launch. 704 blocks = 8 * 88 (bijective
// XCD swizzle). v<512: K/V body (M=16384); v>=512: Q-side (M=4096):
// z=0 -> Qh, z=1 -> Kh title rows, z=2 -> Vh title rows.
// ---------------------------------------------------------------------------
__global__ __launch_bounds__(512, 1) void gemm_all(
    const f16* __restrict__ Qb, const f16* __restrict__ Kb,
    const f16* __restrict__ Vb,
    const f16* __restrict__ Wqb, const f16* __restrict__ Wkb,
    const f16* __restrict__ Wvb,
    const float* __restrict__ bq, const float* __restrict__ bk,
    const float* __restrict__ bv,
    f16* __restrict__ Qh, f16* __restrict__ Kh, f16* __restrict__ Vh)
{
  __shared__ __align__(16) f16 sbuf[65536];   // 128 KiB
  const int bid = blockIdx.x;
  const int v = (bid & 7) * 88 + (bid >> 3);

  const f16* A;
  const f16* W;
  const float* bias;
  f16* C;
  int m0, n0, rowShift, outStride, rowOff;

  if (v < 512) {
    const int z = v >> 8, rem = v & 255;
    A = z ? Vb : Kb;
    W = z ? Wvb : Wkb;
    bias = z ? bv : bk;
    C = z ? Vh : Kh;
    m0 = (rem >> 2) * 256; n0 = (rem & 3) * 256;
    rowShift = 7; outStride = 160; rowOff = 0;
  } else {
    const int u = v - 512;
    const int z = u >> 6, rem = u & 63;
    A = Qb;
    W = (z == 0) ? Wqb : (z == 1) ? Wkb : Wvb;
    bias = (z == 0) ? bq : (z == 1) ? bk : bv;
    C = (z == 0) ? Qh : (z == 1) ? Kh : Vh;
    m0 = (rem >> 2) * 256; n0 = (rem & 3) * 256;
    rowShift = 5;
    outStride = (z == 0) ? 32 : 160;
    rowOff = (z == 0) ? 0 : 128;
  }
  gemm_tile_256(A, W, bias, C, m0, n0, rowShift, outStride, rowOff, sbuf);
}

// ---------------------------------------------------------------------------
// MFMA attention: one block per (b,h), 4 waves. (unchanged)
// ---------------------------------------------------------------------------
__global__ __launch_bounds__(256) void attn_kernel(
    const f16* __restrict__ Qh, const f16* __restrict__ Kh,
    const f16* __restrict__ Vh,
    const float* __restrict__ title, const float* __restrict__ body,
    float* __restrict__ out)
{
  __shared__ __align__(16) f16 Qs[32 * 72];    // stride 144B (b128-friendly)
  __shared__ __align__(16) f16 Ks[160 * 72];   // reused as Ps[32][168] (336B)
  __shared__ __align__(16) f16 Vs[160 * 68];   // stride 136B (2-way max on u16)
  __shared__ float rs[4][32];
  __shared__ float invs[32];

  const int bh = blockIdx.x, b = bh >> 4, h = bh & 15;
  const int t = threadIdx.x, w = t >> 6, lane = t & 63;
  const int c = lane & 15, g = lane >> 4;

  const long long qbase = ((long long)(b * 32) << 10) + h * 64;
  const long long kbase = ((long long)(b * 160) << 10) + h * 64;

  {
    int row = t >> 3, ch = t & 7;
    *(f16x8*)(Qs + row * 72 + ch * 8) =
        *(const f16x8*)(Qh + qbase + (long long)row * 1024 + ch * 8);
  }
#pragma unroll
  for (int r = 0; r < 5; ++r) {
    int i = t + r * 256;
    int row = i >> 3, ch = i & 7;
    *(f16x8*)(Ks + row * 72 + ch * 8) =
        *(const f16x8*)(Kh + kbase + (long long)row * 1024 + ch * 8);
    f16x8 vv = *(const f16x8*)(Vh + kbase + (long long)row * 1024 + ch * 8);
    f16x4 vlo = __builtin_shufflevector(vv, vv, 0, 1, 2, 3);
    f16x4 vhi = __builtin_shufflevector(vv, vv, 4, 5, 6, 7);
    *(f16x4*)(Vs + row * 68 + ch * 8) = vlo;
    *(f16x4*)(Vs + row * 68 + ch * 8 + 4) = vhi;
  }
  __syncthreads();

  f16x8 qf[2][2];
#pragma unroll
  for (int qt = 0; qt < 2; ++qt)
#pragma unroll
    for (int s = 0; s < 2; ++s)
      qf[qt][s] = *(const f16x8*)(Qs + (qt * 16 + c) * 72 + s * 32 + g * 8);

  const int cnt = (w < 2) ? 3 : 2;
  const int tile0 = (w < 2) ? w * 3 : 6 + (w - 2) * 2;

  f16x4 pp[3][2];
  float rsum[2] = {0.f, 0.f};

#pragma unroll
  for (int i = 0; i < 3; ++i) {
    if (i < cnt) {
      const int kt = tile0 + i;
      f16x8 kf0 = *(const f16x8*)(Ks + (kt * 16 + c) * 72 + 0 + g * 8);
      f16x8 kf1 = *(const f16x8*)(Ks + (kt * 16 + c) * 72 + 32 + g * 8);
#pragma unroll
      for (int qt = 0; qt < 2; ++qt) {
        f32x4v s4 = (f32x4v){0.f, 0.f, 0.f, 0.f};
        s4 = __builtin_amdgcn_mfma_f32_16x16x32_f16(kf0, qf[qt][0], s4, 0, 0, 0);
        s4 = __builtin_amdgcn_mfma_f32_16x16x32_f16(kf1, qf[qt][1], s4, 0, 0, 0);
        float4 m4;
        if (kt < 8) {
          m4 = *(const float4*)(body +
                ((long long)(b * 32 + qt * 16 + c)) * 128 + kt * 16 + 4 * g);
        } else {
          m4 = *(const float4*)(title + b * 32 + (kt - 8) * 16 + 4 * g);
        }
        float e0 = __expf(s4[0] * 0.125f) * m4.x;
        float e1 = __expf(s4[1] * 0.125f) * m4.y;
        float e2 = __expf(s4[2] * 0.125f) * m4.z;
        float e3 = __expf(s4[3] * 0.125f) * m4.w;
        rsum[qt] += (e0 + e1) + (e2 + e3);
        f16x4 p4;
        p4.x = (f16)e0; p4.y = (f16)e1; p4.z = (f16)e2; p4.w = (f16)e3;
        pp[i][qt] = p4;
      }
    }
  }

#pragma unroll
  for (int qt = 0; qt < 2; ++qt) {
    rsum[qt] += __shfl_xor(rsum[qt], 16);
    rsum[qt] += __shfl_xor(rsum[qt], 32);
  }
  if (lane < 16) {
    rs[w][c] = rsum[0];
    rs[w][16 + c] = rsum[1];
  }
  __syncthreads();

  f16* Ps = Ks;
#pragma unroll
  for (int i = 0; i < 3; ++i) {
    if (i < cnt) {
      const int kt = tile0 + i;
#pragma unroll
      for (int qt = 0; qt < 2; ++qt)
        *(f16x4*)(Ps + (qt * 16 + c) * 168 + kt * 16 + 4 * g) = pp[i][qt];
    }
  }
  if (t < 32) {
    float ssum = rs[0][t] + rs[1][t] + rs[2][t] + rs[3][t];
    invs[t] = title[b * 32 + t] / (ssum + 1e-8f);
  }
  __syncthreads();

  f32x4v o[2] = {(f32x4v){0.f, 0.f, 0.f, 0.f}, (f32x4v){0.f, 0.f, 0.f, 0.f}};
#pragma unroll
  for (int s = 0; s < 5; ++s) {
    f16x8 vf;
#pragma unroll
    for (int j = 0; j < 8; ++j)
      vf[j] = Vs[(32 * s + 8 * g + j) * 68 + 16 * w + c];
#pragma unroll
    for (int qt = 0; qt < 2; ++qt) {
      f16x8 pf = *(const f16x8*)(Ps + (qt * 16 + c) * 168 + s * 32 + g * 8);
      o[qt] = __builtin_amdgcn_mfma_f32_16x16x32_f16(pf, vf, o[qt], 0, 0, 0);
    }
  }

#pragma unroll
  for (int qt = 0; qt < 2; ++qt) {
#pragma unroll
    for (int v = 0; v < 4; ++v) {
      int q = qt * 16 + 4 * g + v;
      out[((long long)(b * 32 + q) << 10) + h * 64 + 16 * w + c] =
          o[qt][v] * invs[q];
    }
  }
}

// ---------------------------------------------------------------------------
extern "C" void kernel_launch(void* const* d_in, const int* in_sizes, int n_in,
                              void* d_out, int out_size, void* d_ws, size_t ws_size,
                              hipStream_t stream) {
  const float* Q_seq = (const float*)d_in[0];
  const float* K_seq = (const float*)d_in[1];
  const float* V_seq = (const float*)d_in[2];
  const float* title = (const float*)d_in[3];
  const float* body  = (const float*)d_in[4];
  const float* Wq = (const float*)d_in[5];
  const float* bq = (const float*)d_in[6];
  const float* Wk = (const float*)d_in[7];
  const float* bk = (const float*)d_in[8];
  const float* Wv = (const float*)d_in[9];
  const float* bv = (const float*)d_in[10];
  float* out = (float*)d_out;

  f16* ws = (f16*)d_ws;
  f16* Qb  = ws;
  f16* Kb  = Qb + 4194304;
  f16* Vb  = Kb + 16777216;
  f16* Wqb = Vb + 16777216;
  f16* Wkb = Wqb + 1048576;
  f16* Wvb = Wkb + 1048576;
  f16* Qh  = Wvb + 1048576;
  f16* Kh  = Qh + 4194304;
  f16* Vh  = Kh + 20971520;

  prep_kernel<<<19968, 256, 0, stream>>>(Q_seq, K_seq, V_seq, Wq, Wk, Wv,
                                         Qb, Kb, Vb, Wqb, Wkb, Wvb);
  gemm_all<<<704, 512, 0, stream>>>(Qb, Kb, Vb, Wqb, Wkb, Wvb,
                                    bq, bk, bv, Qh, Kh, Vh);
  attn_kernel<<<2048, 256, 0, stream>>>(Qh, Kh, Vh, title, body, out);
}